// Round 8
// baseline (589.451 us; speedup 1.0000x reference)
//
#include <hip/hip_runtime.h>
#include <hip/hip_bf16.h>

typedef short bf16x8_t __attribute__((ext_vector_type(8)));
typedef float f32x4_t __attribute__((ext_vector_type(4)));

#define SDIM 2048
#define DDIM 64
#define NBH  48

__device__ __forceinline__ unsigned short f2bf(float f) {
    return __builtin_bit_cast(unsigned short, (__bf16)f);
}
__device__ __forceinline__ unsigned int pack2(float lo, float hi) {
    return ((unsigned int)f2bf(hi) << 16) | (unsigned int)f2bf(lo);
}
__device__ __forceinline__ bf16x8_t pack8(f32x4_t a, f32x4_t b) {
    bf16x8_t r;
    r[0] = (short)f2bf(a[0]); r[1] = (short)f2bf(a[1]);
    r[2] = (short)f2bf(a[2]); r[3] = (short)f2bf(a[3]);
    r[4] = (short)f2bf(b[0]); r[5] = (short)f2bf(b[1]);
    r[6] = (short)f2bf(b[2]); r[7] = (short)f2bf(b[3]);
    return r;
}
__device__ __forceinline__ bf16x8_t pack8s(f32x4_t a, f32x4_t b, float s) {
    bf16x8_t r;
    r[0] = (short)f2bf(a[0] * s); r[1] = (short)f2bf(a[1] * s);
    r[2] = (short)f2bf(a[2] * s); r[3] = (short)f2bf(a[3] * s);
    r[4] = (short)f2bf(b[0] * s); r[5] = (short)f2bf(b[1] * s);
    r[6] = (short)f2bf(b[2] * s); r[7] = (short)f2bf(b[3] * s);
    return r;
}
struct uint4s { unsigned int x, y, z, w; };

// ---------- prep 1: K fp32 -> bf16 (row-major) ----------
__global__ __launch_bounds__(256) void cvt_k_kernel(const float* __restrict__ K,
                                                    unsigned short* __restrict__ Kb) {
    size_t i = ((size_t)blockIdx.x * 256 + threadIdx.x) * 8;
    f32x4_t a = *(const f32x4_t*)(K + i);
    f32x4_t b = *(const f32x4_t*)(K + i + 4);
    *(bf16x8_t*)(Kb + i) = pack8(a, b);
}

// ---------- prep 2: V fp32 [bh][k][d] -> bf16 V^T [bh][d][k] ----------
__global__ __launch_bounds__(256) void tr_v_kernel(const float* __restrict__ V,
                                                   unsigned short* __restrict__ VT) {
    __shared__ unsigned short lt[64 * 72];
    const int bh = blockIdx.x >> 5;
    const int kt = blockIdx.x & 31;
    const float* Vb = V + (size_t)bh * (SDIM * DDIM) + (size_t)kt * 64 * DDIM;
    unsigned short* VTb = VT + (size_t)bh * (DDIM * SDIM) + kt * 64;
    const int t = threadIdx.x;
    {
        const int kl = t >> 2, dg = t & 3;
        const float* vp = Vb + kl * DDIM + dg * 16;
        f32x4_t v0 = *(const f32x4_t*)vp;
        f32x4_t v1 = *(const f32x4_t*)(vp + 4);
        f32x4_t v2 = *(const f32x4_t*)(vp + 8);
        f32x4_t v3 = *(const f32x4_t*)(vp + 12);
#pragma unroll
        for (int j = 0; j < 16; ++j) {
            float f = (j < 4) ? v0[j] : (j < 8) ? v1[j - 4] : (j < 12) ? v2[j - 8] : v3[j - 12];
            lt[(dg * 16 + j) * 72 + kl] = f2bf(f);
        }
    }
    __syncthreads();
    {
        const int d = t >> 2, kg = t & 3;
        bf16x8_t w0 = *(const bf16x8_t*)&lt[d * 72 + kg * 16];
        bf16x8_t w1 = *(const bf16x8_t*)&lt[d * 72 + kg * 16 + 8];
        *(bf16x8_t*)(VTb + (size_t)d * SDIM + kg * 16) = w0;
        *(bf16x8_t*)(VTb + (size_t)d * SDIM + kg * 16 + 8) = w1;
    }
}

// ---------- main: swapped QK^T, shfl P-redistribution, K double-buffered ----------
__global__ __launch_bounds__(128, 4) void sdpa_main_kernel(
    const float* __restrict__ Q, const unsigned short* __restrict__ Kb,
    const unsigned short* __restrict__ VT, float* __restrict__ out,
    float* __restrict__ attn)
{
    const int bid = blockIdx.x;
    const int bh  = bid >> 6;      // 48
    const int qt  = bid & 63;      // 64 tiles of 32 rows
    const int tid = threadIdx.x;
    const int lane = tid & 63;
    const int wv   = tid >> 6;     // 0..1
    const int l15  = lane & 15;    // this lane's q-row (swapped layout)
    const int hi   = lane >> 4;    // 0..3
    const int qbase = qt * 32 + wv * 16;

    const unsigned short* KbB = Kb + (size_t)bh * (SDIM * DDIM);
    const unsigned short* VTb = VT + (size_t)bh * (DDIM * SDIM);
    float* outW  = out  + ((size_t)bh * SDIM + qbase) * DDIM;
    float* attnW = attn + (size_t)bh * SDIM * SDIM + (size_t)qbase * SDIM;

    const float SC = 0.18033688011112042f;  // (1/sqrt(64)) * log2(e)

    // ---- Q fragment (B operand), pre-scaled by SC
    const float* qp = Q + ((size_t)bh * SDIM + qbase + l15) * DDIM + hi * 8;
    const bf16x8_t aq0 = pack8s(*(const f32x4_t*)qp,        *(const f32x4_t*)(qp + 4), SC);
    const bf16x8_t aq1 = pack8s(*(const f32x4_t*)(qp + 32), *(const f32x4_t*)(qp + 36), SC);

    // ================= pass A: row sums (lane-local q), 64 keys/iter =================
    float rs = 0.f;
    {
        const unsigned short* kp0 = KbB + (size_t)l15 * DDIM + hi * 8;
        bf16x8_t cur[8];
#pragma unroll
        for (int s = 0; s < 4; ++s) {
            cur[s * 2]     = *(const bf16x8_t*)(kp0 + (size_t)(s * 16) * DDIM);
            cur[s * 2 + 1] = *(const bf16x8_t*)(kp0 + (size_t)(s * 16) * DDIM + 32);
        }
        for (int ci = 0; ci < 32; ++ci) {
            bf16x8_t nxt[8];
#pragma unroll
            for (int s = 0; s < 8; ++s) nxt[s] = cur[s];
            if (ci < 31) {
                const unsigned short* np = kp0 + (size_t)(ci + 1) * 64 * DDIM;
#pragma unroll
                for (int s = 0; s < 4; ++s) {
                    nxt[s * 2]     = *(const bf16x8_t*)(np + (size_t)(s * 16) * DDIM);
                    nxt[s * 2 + 1] = *(const bf16x8_t*)(np + (size_t)(s * 16) * DDIM + 32);
                }
            }
#pragma unroll
            for (int s = 0; s < 4; ++s) {
                f32x4_t acc = {0.f, 0.f, 0.f, 0.f};
                acc = __builtin_amdgcn_mfma_f32_16x16x32_bf16(cur[s * 2],     aq0, acc, 0, 0, 0);
                acc = __builtin_amdgcn_mfma_f32_16x16x32_bf16(cur[s * 2 + 1], aq1, acc, 0, 0, 0);
                rs += __builtin_amdgcn_exp2f(acc[0]) + __builtin_amdgcn_exp2f(acc[1])
                    + __builtin_amdgcn_exp2f(acc[2]) + __builtin_amdgcn_exp2f(acc[3]);
            }
#pragma unroll
            for (int s = 0; s < 8; ++s) cur[s] = nxt[s];
        }
    }
    rs += __shfl_xor(rs, 16);
    rs += __shfl_xor(rs, 32);
    const float nlg = __builtin_amdgcn_logf(rs);  // log2 of row sum (lane-local q)

    // ================= pass B: 32 keys/iter, K double-buffered =================
    f32x4_t oacc[4] = {{0.f,0.f,0.f,0.f},{0.f,0.f,0.f,0.f},{0.f,0.f,0.f,0.f},{0.f,0.f,0.f,0.f}};
    f32x4_t pprev[2];

    const int laneA = l15 + ((hi & 1) << 5);
    const int laneB = laneA + 16;
    const bool selHi = (hi >> 1) != 0;

    // prologue: K frags for kb=0
    bf16x8_t kc[4];
    {
        const unsigned short* kp = KbB + (size_t)l15 * DDIM + hi * 8;
        kc[0] = *(const bf16x8_t*)kp;
        kc[1] = *(const bf16x8_t*)(kp + 32);
        kc[2] = *(const bf16x8_t*)(kp + (size_t)16 * DDIM);
        kc[3] = *(const bf16x8_t*)(kp + (size_t)16 * DDIM + 32);
    }

    for (int kb = 0; kb < 64; ++kb) {
        const int kbase = kb * 32;

        // --- phase 0: prefetch K for kb+1 (full iteration of slack)
        bf16x8_t kn[4];
        {
            const int nb = (kb < 63) ? kbase + 32 : kbase;  // clamp (redundant load on last)
            const unsigned short* kp = KbB + (size_t)(nb + l15) * DDIM + hi * 8;
            kn[0] = *(const bf16x8_t*)kp;
            kn[1] = *(const bf16x8_t*)(kp + 32);
            kn[2] = *(const bf16x8_t*)(kp + (size_t)16 * DDIM);
            kn[3] = *(const bf16x8_t*)(kp + (size_t)16 * DDIM + 32);
        }
        // --- V for this iter (consumed last -> slack = QK^T+softmax+shfl)
        bf16x8_t vv[4];
        {
            const unsigned short* vp = VTb + (size_t)l15 * SDIM + kbase + hi * 8;
#pragma unroll
            for (int dt = 0; dt < 4; ++dt)
                vv[dt] = *(const bf16x8_t*)(vp + (size_t)(dt * 16) * SDIM);
        }

        // --- attn stores for kb-1 (younger than all loads that get waited on)
        if (kb > 0) {
            float* ap = attnW + (size_t)l15 * SDIM + (kbase - 32) + hi * 4;
            *(f32x4_t*)ap = pprev[0];
            *(f32x4_t*)(ap + 16) = pprev[1];
        }

        // --- QK^T (swapped: D rows = keys, cols = q)
        f32x4_t acc0 = {0.f,0.f,0.f,0.f}, acc1 = {0.f,0.f,0.f,0.f};
        __builtin_amdgcn_s_setprio(1);
        acc0 = __builtin_amdgcn_mfma_f32_16x16x32_bf16(kc[0], aq0, acc0, 0, 0, 0);
        acc0 = __builtin_amdgcn_mfma_f32_16x16x32_bf16(kc[1], aq1, acc0, 0, 0, 0);
        acc1 = __builtin_amdgcn_mfma_f32_16x16x32_bf16(kc[2], aq0, acc1, 0, 0, 0);
        acc1 = __builtin_amdgcn_mfma_f32_16x16x32_bf16(kc[3], aq1, acc1, 0, 0, 0);
        __builtin_amdgcn_s_setprio(0);

        // --- softmax -> normalized p
        f32x4_t p0, p1;
#pragma unroll
        for (int r = 0; r < 4; ++r) {
            p0[r] = __builtin_amdgcn_exp2f(acc0[r] - nlg);
            p1[r] = __builtin_amdgcn_exp2f(acc1[r] - nlg);
        }

        // --- pack to bf16 pairs
        unsigned int w0[2], w1[2];
        w0[0] = pack2(p0[0], p0[1]); w1[0] = pack2(p0[2], p0[3]);
        w0[1] = pack2(p1[0], p1[1]); w1[1] = pack2(p1[2], p1[3]);

        // --- shfl redistribution -> PV A-fragment (keys hi*8+{0..7})
        bf16x8_t af;
        {
            unsigned int W0a = (unsigned int)__shfl((int)w0[0], laneA);
            unsigned int W0b = (unsigned int)__shfl((int)w0[1], laneA);
            unsigned int W1a = (unsigned int)__shfl((int)w1[0], laneA);
            unsigned int W1b = (unsigned int)__shfl((int)w1[1], laneA);
            unsigned int W2a = (unsigned int)__shfl((int)w0[0], laneB);
            unsigned int W2b = (unsigned int)__shfl((int)w0[1], laneB);
            unsigned int W3a = (unsigned int)__shfl((int)w1[0], laneB);
            unsigned int W3b = (unsigned int)__shfl((int)w1[1], laneB);
            uint4s W;
            W.x = selHi ? W0b : W0a;
            W.y = selHi ? W1b : W1a;
            W.z = selHi ? W2b : W2a;
            W.w = selHi ? W3b : W3a;
            af = __builtin_bit_cast(bf16x8_t, W);
        }

        // --- PV
        __builtin_amdgcn_s_setprio(1);
#pragma unroll
        for (int dt = 0; dt < 4; ++dt)
            oacc[dt] = __builtin_amdgcn_mfma_f32_16x16x32_bf16(af, vv[dt], oacc[dt], 0, 0, 0);
        __builtin_amdgcn_s_setprio(0);

        pprev[0] = p0; pprev[1] = p1;
#pragma unroll
        for (int s = 0; s < 4; ++s) kc[s] = kn[s];
    }
    // --- final attn stores
    {
        float* ap = attnW + (size_t)l15 * SDIM + (SDIM - 32) + hi * 4;
        *(f32x4_t*)ap = pprev[0];
        *(f32x4_t*)(ap + 16) = pprev[1];
    }

    // --- epilogue: output (normalized)
#pragma unroll
    for (int dt = 0; dt < 4; ++dt) {
#pragma unroll
        for (int r = 0; r < 4; ++r)
            outW[(size_t)(hi * 4 + r) * DDIM + dt * 16 + l15] = oacc[dt][r];
    }
}

extern "C" void kernel_launch(void* const* d_in, const int* in_sizes, int n_in,
                              void* d_out, int out_size, void* d_ws, size_t ws_size,
                              hipStream_t stream) {
    const float* Q = (const float*)d_in[0];
    const float* K = (const float*)d_in[1];
    const float* V = (const float*)d_in[2];
    float* out  = (float*)d_out;
    float* attn = out + (size_t)NBH * SDIM * DDIM;

    unsigned short* Kb = (unsigned short*)d_ws;
    unsigned short* VT = Kb + (size_t)NBH * SDIM * DDIM;

    cvt_k_kernel<<<dim3((NBH * SDIM * DDIM) / (256 * 8)), dim3(256), 0, stream>>>(K, Kb);
    tr_v_kernel<<<dim3(NBH * 32), dim3(256), 0, stream>>>(V, VT);

    sdpa_main_kernel<<<dim3(NBH * 64), dim3(128), 0, stream>>>(Q, Kb, VT, out, attn);
}

// Round 9
// 448.541 us; speedup vs baseline: 1.3142x; 1.3142x over previous
//
#include <hip/hip_runtime.h>
#include <hip/hip_bf16.h>

typedef short bf16x8_t __attribute__((ext_vector_type(8)));
typedef float f32x4_t __attribute__((ext_vector_type(4)));

#define SDIM 2048
#define DDIM 64
#define NBH  48

__device__ __forceinline__ unsigned short f2bf(float f) {
    return __builtin_bit_cast(unsigned short, (__bf16)f);
}
__device__ __forceinline__ unsigned int pack2(float lo, float hi) {
    return ((unsigned int)f2bf(hi) << 16) | (unsigned int)f2bf(lo);
}
__device__ __forceinline__ bf16x8_t pack8(f32x4_t a, f32x4_t b) {
    bf16x8_t r;
    r[0] = (short)f2bf(a[0]); r[1] = (short)f2bf(a[1]);
    r[2] = (short)f2bf(a[2]); r[3] = (short)f2bf(a[3]);
    r[4] = (short)f2bf(b[0]); r[5] = (short)f2bf(b[1]);
    r[6] = (short)f2bf(b[2]); r[7] = (short)f2bf(b[3]);
    return r;
}
__device__ __forceinline__ bf16x8_t pack8s(f32x4_t a, f32x4_t b, float s) {
    bf16x8_t r;
    r[0] = (short)f2bf(a[0] * s); r[1] = (short)f2bf(a[1] * s);
    r[2] = (short)f2bf(a[2] * s); r[3] = (short)f2bf(a[3] * s);
    r[4] = (short)f2bf(b[0] * s); r[5] = (short)f2bf(b[1] * s);
    r[6] = (short)f2bf(b[2] * s); r[7] = (short)f2bf(b[3] * s);
    return r;
}
struct uint4s { unsigned int x, y, z, w; };

// ---------- prep 1: K fp32 -> bf16 (row-major) ----------
__global__ __launch_bounds__(256) void cvt_k_kernel(const float* __restrict__ K,
                                                    unsigned short* __restrict__ Kb) {
    size_t i = ((size_t)blockIdx.x * 256 + threadIdx.x) * 8;
    f32x4_t a = *(const f32x4_t*)(K + i);
    f32x4_t b = *(const f32x4_t*)(K + i + 4);
    *(bf16x8_t*)(Kb + i) = pack8(a, b);
}

// ---------- prep 2: V fp32 [bh][k][d] -> bf16 V^T [bh][d][k] ----------
__global__ __launch_bounds__(256) void tr_v_kernel(const float* __restrict__ V,
                                                   unsigned short* __restrict__ VT) {
    __shared__ unsigned short lt[64 * 72];
    const int bh = blockIdx.x >> 5;
    const int kt = blockIdx.x & 31;
    const float* Vb = V + (size_t)bh * (SDIM * DDIM) + (size_t)kt * 64 * DDIM;
    unsigned short* VTb = VT + (size_t)bh * (DDIM * SDIM) + kt * 64;
    const int t = threadIdx.x;
    {
        const int kl = t >> 2, dg = t & 3;
        const float* vp = Vb + kl * DDIM + dg * 16;
        f32x4_t v0 = *(const f32x4_t*)vp;
        f32x4_t v1 = *(const f32x4_t*)(vp + 4);
        f32x4_t v2 = *(const f32x4_t*)(vp + 8);
        f32x4_t v3 = *(const f32x4_t*)(vp + 12);
#pragma unroll
        for (int j = 0; j < 16; ++j) {
            float f = (j < 4) ? v0[j] : (j < 8) ? v1[j - 4] : (j < 12) ? v2[j - 8] : v3[j - 12];
            lt[(dg * 16 + j) * 72 + kl] = f2bf(f);
        }
    }
    __syncthreads();
    {
        const int d = t >> 2, kg = t & 3;
        bf16x8_t w0 = *(const bf16x8_t*)&lt[d * 72 + kg * 16];
        bf16x8_t w1 = *(const bf16x8_t*)&lt[d * 72 + kg * 16 + 8];
        *(bf16x8_t*)(VTb + (size_t)d * SDIM + kg * 16) = w0;
        *(bf16x8_t*)(VTb + (size_t)d * SDIM + kg * 16 + 8) = w1;
    }
}

// ---------- main: 32 q-rows/wave (2 sub-tiles share K/V loads) ----------
__global__ __launch_bounds__(128, 3) void sdpa_main_kernel(
    const float* __restrict__ Q, const unsigned short* __restrict__ Kb,
    const unsigned short* __restrict__ VT, float* __restrict__ out,
    float* __restrict__ attn)
{
    const int bid = blockIdx.x;
    const int bh  = bid >> 5;      // 48
    const int qt  = bid & 31;      // 32 tiles of 64 q
    const int tid = threadIdx.x;
    const int lane = tid & 63;
    const int wv   = tid >> 6;     // 0..1
    const int l15  = lane & 15;
    const int hi   = lane >> 4;    // 0..3
    const int qbase = qt * 64 + wv * 32;   // this wave owns 32 q-rows

    const unsigned short* KbB = Kb + (size_t)bh * (SDIM * DDIM);
    const unsigned short* VTb = VT + (size_t)bh * (DDIM * SDIM);
    float* outW  = out  + ((size_t)bh * SDIM + qbase) * DDIM;
    float* attnW = attn + (size_t)bh * SDIM * SDIM + (size_t)qbase * SDIM;

    const float SC = 0.18033688011112042f;  // (1/sqrt(64)) * log2(e)

    // ---- Q fragments for both sub-tiles (B operand), pre-scaled by SC
    const float* qp0 = Q + ((size_t)bh * SDIM + qbase + l15) * DDIM + hi * 8;
    const float* qp1 = qp0 + (size_t)16 * DDIM;
    const bf16x8_t aq0_0 = pack8s(*(const f32x4_t*)qp0,        *(const f32x4_t*)(qp0 + 4), SC);
    const bf16x8_t aq1_0 = pack8s(*(const f32x4_t*)(qp0 + 32), *(const f32x4_t*)(qp0 + 36), SC);
    const bf16x8_t aq0_1 = pack8s(*(const f32x4_t*)qp1,        *(const f32x4_t*)(qp1 + 4), SC);
    const bf16x8_t aq1_1 = pack8s(*(const f32x4_t*)(qp1 + 32), *(const f32x4_t*)(qp1 + 36), SC);

    // ================= pass A: row sums, K frags shared by both tiles =================
    float rs0 = 0.f, rs1 = 0.f;
    {
        const unsigned short* kp0 = KbB + (size_t)l15 * DDIM + hi * 8;
        bf16x8_t cur[8];
#pragma unroll
        for (int s = 0; s < 4; ++s) {
            cur[s * 2]     = *(const bf16x8_t*)(kp0 + (size_t)(s * 16) * DDIM);
            cur[s * 2 + 1] = *(const bf16x8_t*)(kp0 + (size_t)(s * 16) * DDIM + 32);
        }
        for (int ci = 0; ci < 32; ++ci) {
            bf16x8_t nxt[8];
#pragma unroll
            for (int s = 0; s < 8; ++s) nxt[s] = cur[s];
            if (ci < 31) {
                const unsigned short* np = kp0 + (size_t)(ci + 1) * 64 * DDIM;
#pragma unroll
                for (int s = 0; s < 4; ++s) {
                    nxt[s * 2]     = *(const bf16x8_t*)(np + (size_t)(s * 16) * DDIM);
                    nxt[s * 2 + 1] = *(const bf16x8_t*)(np + (size_t)(s * 16) * DDIM + 32);
                }
            }
            __builtin_amdgcn_s_setprio(1);
#pragma unroll
            for (int s = 0; s < 4; ++s) {
                f32x4_t a0 = {0.f, 0.f, 0.f, 0.f}, a1 = {0.f, 0.f, 0.f, 0.f};
                a0 = __builtin_amdgcn_mfma_f32_16x16x32_bf16(cur[s * 2],     aq0_0, a0, 0, 0, 0);
                a0 = __builtin_amdgcn_mfma_f32_16x16x32_bf16(cur[s * 2 + 1], aq1_0, a0, 0, 0, 0);
                a1 = __builtin_amdgcn_mfma_f32_16x16x32_bf16(cur[s * 2],     aq0_1, a1, 0, 0, 0);
                a1 = __builtin_amdgcn_mfma_f32_16x16x32_bf16(cur[s * 2 + 1], aq1_1, a1, 0, 0, 0);
                rs0 += __builtin_amdgcn_exp2f(a0[0]) + __builtin_amdgcn_exp2f(a0[1])
                     + __builtin_amdgcn_exp2f(a0[2]) + __builtin_amdgcn_exp2f(a0[3]);
                rs1 += __builtin_amdgcn_exp2f(a1[0]) + __builtin_amdgcn_exp2f(a1[1])
                     + __builtin_amdgcn_exp2f(a1[2]) + __builtin_amdgcn_exp2f(a1[3]);
            }
            __builtin_amdgcn_s_setprio(0);
#pragma unroll
            for (int s = 0; s < 8; ++s) cur[s] = nxt[s];
        }
    }
    rs0 += __shfl_xor(rs0, 16); rs0 += __shfl_xor(rs0, 32);
    rs1 += __shfl_xor(rs1, 16); rs1 += __shfl_xor(rs1, 32);
    const float nlg0 = __builtin_amdgcn_logf(rs0);
    const float nlg1 = __builtin_amdgcn_logf(rs1);

    // ================= pass B: 32 keys/iter, both tiles share K/V =================
    f32x4_t oacc0[4] = {{0.f,0.f,0.f,0.f},{0.f,0.f,0.f,0.f},{0.f,0.f,0.f,0.f},{0.f,0.f,0.f,0.f}};
    f32x4_t oacc1[4] = {{0.f,0.f,0.f,0.f},{0.f,0.f,0.f,0.f},{0.f,0.f,0.f,0.f},{0.f,0.f,0.f,0.f}};
    f32x4_t pprev0[2], pprev1[2];

    const int laneA = l15 + ((hi & 1) << 5);
    const int laneB = laneA + 16;
    const bool selHi = (hi >> 1) != 0;

    // prologue: K frags for kb=0
    bf16x8_t kc[4];
    {
        const unsigned short* kp = KbB + (size_t)l15 * DDIM + hi * 8;
        kc[0] = *(const bf16x8_t*)kp;
        kc[1] = *(const bf16x8_t*)(kp + 32);
        kc[2] = *(const bf16x8_t*)(kp + (size_t)16 * DDIM);
        kc[3] = *(const bf16x8_t*)(kp + (size_t)16 * DDIM + 32);
    }

    for (int kb = 0; kb < 64; ++kb) {
        const int kbase = kb * 32;

        // --- V first (consumed this iter; oldest among this iter's loads)
        bf16x8_t vv[4];
        {
            const unsigned short* vp = VTb + (size_t)l15 * SDIM + kbase + hi * 8;
#pragma unroll
            for (int dt = 0; dt < 4; ++dt)
                vv[dt] = *(const bf16x8_t*)(vp + (size_t)(dt * 16) * SDIM);
        }
        // --- K prefetch for kb+1 (consumed next iter)
        bf16x8_t kn[4];
        {
            const int nb = (kb < 63) ? kbase + 32 : kbase;
            const unsigned short* kp = KbB + (size_t)(nb + l15) * DDIM + hi * 8;
            kn[0] = *(const bf16x8_t*)kp;
            kn[1] = *(const bf16x8_t*)(kp + 32);
            kn[2] = *(const bf16x8_t*)(kp + (size_t)16 * DDIM);
            kn[3] = *(const bf16x8_t*)(kp + (size_t)16 * DDIM + 32);
        }

        // --- attn stores for kb-1 (younger than all loads -> never gate waits)
        if (kb > 0) {
            float* ap0 = attnW + (size_t)l15 * SDIM + (kbase - 32) + hi * 4;
            float* ap1 = ap0 + (size_t)16 * SDIM;
            *(f32x4_t*)ap0 = pprev0[0];
            *(f32x4_t*)(ap0 + 16) = pprev0[1];
            *(f32x4_t*)ap1 = pprev1[0];
            *(f32x4_t*)(ap1 + 16) = pprev1[1];
        }

        // --- QK^T both tiles (swapped: D rows = keys, cols = q)
        f32x4_t a00 = {0.f,0.f,0.f,0.f}, a01 = {0.f,0.f,0.f,0.f};
        f32x4_t a10 = {0.f,0.f,0.f,0.f}, a11 = {0.f,0.f,0.f,0.f};
        __builtin_amdgcn_s_setprio(1);
        a00 = __builtin_amdgcn_mfma_f32_16x16x32_bf16(kc[0], aq0_0, a00, 0, 0, 0);
        a00 = __builtin_amdgcn_mfma_f32_16x16x32_bf16(kc[1], aq1_0, a00, 0, 0, 0);
        a01 = __builtin_amdgcn_mfma_f32_16x16x32_bf16(kc[2], aq0_0, a01, 0, 0, 0);
        a01 = __builtin_amdgcn_mfma_f32_16x16x32_bf16(kc[3], aq1_0, a01, 0, 0, 0);
        a10 = __builtin_amdgcn_mfma_f32_16x16x32_bf16(kc[0], aq0_1, a10, 0, 0, 0);
        a10 = __builtin_amdgcn_mfma_f32_16x16x32_bf16(kc[1], aq1_1, a10, 0, 0, 0);
        a11 = __builtin_amdgcn_mfma_f32_16x16x32_bf16(kc[2], aq0_1, a11, 0, 0, 0);
        a11 = __builtin_amdgcn_mfma_f32_16x16x32_bf16(kc[3], aq1_1, a11, 0, 0, 0);
        __builtin_amdgcn_s_setprio(0);

        // --- softmax -> normalized p (both tiles)
        f32x4_t p00, p01, p10, p11;
#pragma unroll
        for (int r = 0; r < 4; ++r) {
            p00[r] = __builtin_amdgcn_exp2f(a00[r] - nlg0);
            p01[r] = __builtin_amdgcn_exp2f(a01[r] - nlg0);
            p10[r] = __builtin_amdgcn_exp2f(a10[r] - nlg1);
            p11[r] = __builtin_amdgcn_exp2f(a11[r] - nlg1);
        }

        // --- pack + shfl redistribution (per tile, same verified mapping)
        bf16x8_t af0, af1;
        {
            unsigned int w00 = pack2(p00[0], p00[1]), w10 = pack2(p00[2], p00[3]);
            unsigned int w01 = pack2(p01[0], p01[1]), w11 = pack2(p01[2], p01[3]);
            unsigned int W0a = (unsigned int)__shfl((int)w00, laneA);
            unsigned int W0b = (unsigned int)__shfl((int)w01, laneA);
            unsigned int W1a = (unsigned int)__shfl((int)w10, laneA);
            unsigned int W1b = (unsigned int)__shfl((int)w11, laneA);
            unsigned int W2a = (unsigned int)__shfl((int)w00, laneB);
            unsigned int W2b = (unsigned int)__shfl((int)w01, laneB);
            unsigned int W3a = (unsigned int)__shfl((int)w10, laneB);
            unsigned int W3b = (unsigned int)__shfl((int)w11, laneB);
            uint4s W;
            W.x = selHi ? W0b : W0a;
            W.y = selHi ? W1b : W1a;
            W.z = selHi ? W2b : W2a;
            W.w = selHi ? W3b : W3a;
            af0 = __builtin_bit_cast(bf16x8_t, W);
        }
        {
            unsigned int w00 = pack2(p10[0], p10[1]), w10 = pack2(p10[2], p10[3]);
            unsigned int w01 = pack2(p11[0], p11[1]), w11 = pack2(p11[2], p11[3]);
            unsigned int W0a = (unsigned int)__shfl((int)w00, laneA);
            unsigned int W0b = (unsigned int)__shfl((int)w01, laneA);
            unsigned int W1a = (unsigned int)__shfl((int)w10, laneA);
            unsigned int W1b = (unsigned int)__shfl((int)w11, laneA);
            unsigned int W2a = (unsigned int)__shfl((int)w00, laneB);
            unsigned int W2b = (unsigned int)__shfl((int)w01, laneB);
            unsigned int W3a = (unsigned int)__shfl((int)w10, laneB);
            unsigned int W3b = (unsigned int)__shfl((int)w11, laneB);
            uint4s W;
            W.x = selHi ? W0b : W0a;
            W.y = selHi ? W1b : W1a;
            W.z = selHi ? W2b : W2a;
            W.w = selHi ? W3b : W3a;
            af1 = __builtin_bit_cast(bf16x8_t, W);
        }

        // --- PV both tiles (vv shared)
        __builtin_amdgcn_s_setprio(1);
#pragma unroll
        for (int dt = 0; dt < 4; ++dt) {
            oacc0[dt] = __builtin_amdgcn_mfma_f32_16x16x32_bf16(af0, vv[dt], oacc0[dt], 0, 0, 0);
            oacc1[dt] = __builtin_amdgcn_mfma_f32_16x16x32_bf16(af1, vv[dt], oacc1[dt], 0, 0, 0);
        }
        __builtin_amdgcn_s_setprio(0);

        pprev0[0] = p00; pprev0[1] = p01;
        pprev1[0] = p10; pprev1[1] = p11;
#pragma unroll
        for (int s = 0; s < 4; ++s) kc[s] = kn[s];
    }
    // --- final attn stores
    {
        float* ap0 = attnW + (size_t)l15 * SDIM + (SDIM - 32) + hi * 4;
        float* ap1 = ap0 + (size_t)16 * SDIM;
        *(f32x4_t*)ap0 = pprev0[0];
        *(f32x4_t*)(ap0 + 16) = pprev0[1];
        *(f32x4_t*)ap1 = pprev1[0];
        *(f32x4_t*)(ap1 + 16) = pprev1[1];
    }

    // --- epilogue: output (normalized)
#pragma unroll
    for (int dt = 0; dt < 4; ++dt) {
#pragma unroll
        for (int r = 0; r < 4; ++r) {
            outW[(size_t)(hi * 4 + r) * DDIM + dt * 16 + l15] = oacc0[dt][r];
            outW[(size_t)(16 + hi * 4 + r) * DDIM + dt * 16 + l15] = oacc1[dt][r];
        }
    }
}

extern "C" void kernel_launch(void* const* d_in, const int* in_sizes, int n_in,
                              void* d_out, int out_size, void* d_ws, size_t ws_size,
                              hipStream_t stream) {
    const float* Q = (const float*)d_in[0];
    const float* K = (const float*)d_in[1];
    const float* V = (const float*)d_in[2];
    float* out  = (float*)d_out;
    float* attn = out + (size_t)NBH * SDIM * DDIM;

    unsigned short* Kb = (unsigned short*)d_ws;
    unsigned short* VT = Kb + (size_t)NBH * SDIM * DDIM;

    cvt_k_kernel<<<dim3((NBH * SDIM * DDIM) / (256 * 8)), dim3(256), 0, stream>>>(K, Kb);
    tr_v_kernel<<<dim3(NBH * 32), dim3(256), 0, stream>>>(V, VT);

    sdpa_main_kernel<<<dim3(NBH * 32), dim3(128), 0, stream>>>(Q, Kb, VT, out, attn);
}

// Round 10
// 250.976 us; speedup vs baseline: 2.3486x; 1.7872x over previous
//
#include <hip/hip_runtime.h>
#include <hip/hip_bf16.h>

typedef short bf16x8_t __attribute__((ext_vector_type(8)));
typedef float f32x4_t __attribute__((ext_vector_type(4)));

#define SDIM 2048
#define DDIM 64
#define KBLK 64
#define NIT  (SDIM / KBLK)
#define NBH  48

__device__ __forceinline__ unsigned short f2bf(float f) {
    return __builtin_bit_cast(unsigned short, (__bf16)f);
}
__device__ __forceinline__ unsigned int pack2(float lo, float hi) {
    return ((unsigned int)f2bf(hi) << 16) | (unsigned int)f2bf(lo);
}
__device__ __forceinline__ bf16x8_t pack8(f32x4_t a, f32x4_t b) {
    bf16x8_t r;
    r[0] = (short)f2bf(a[0]); r[1] = (short)f2bf(a[1]);
    r[2] = (short)f2bf(a[2]); r[3] = (short)f2bf(a[3]);
    r[4] = (short)f2bf(b[0]); r[5] = (short)f2bf(b[1]);
    r[6] = (short)f2bf(b[2]); r[7] = (short)f2bf(b[3]);
    return r;
}
__device__ __forceinline__ bf16x8_t pack8s(f32x4_t a, f32x4_t b, float s) {
    bf16x8_t r;
    r[0] = (short)f2bf(a[0] * s); r[1] = (short)f2bf(a[1] * s);
    r[2] = (short)f2bf(a[2] * s); r[3] = (short)f2bf(a[3] * s);
    r[4] = (short)f2bf(b[0] * s); r[5] = (short)f2bf(b[1] * s);
    r[6] = (short)f2bf(b[2] * s); r[7] = (short)f2bf(b[3] * s);
    return r;
}
struct uint4s { unsigned int x, y, z, w; };

__device__ __forceinline__ void lds_sync() {
    asm volatile("s_waitcnt lgkmcnt(0)" ::: "memory");
    __builtin_amdgcn_s_barrier();
    asm volatile("" ::: "memory");
}

// ---------- prep 1: K fp32 -> bf16 (row-major) ----------
__global__ __launch_bounds__(256) void cvt_k_kernel(const float* __restrict__ K,
                                                    unsigned short* __restrict__ Kb) {
    size_t i = ((size_t)blockIdx.x * 256 + threadIdx.x) * 8;
    f32x4_t a = *(const f32x4_t*)(K + i);
    f32x4_t b = *(const f32x4_t*)(K + i + 4);
    *(bf16x8_t*)(Kb + i) = pack8(a, b);
}

// ---------- prep 2: V fp32 [bh][k][d] -> bf16 V^T [bh][d][k] ----------
__global__ __launch_bounds__(256) void tr_v_kernel(const float* __restrict__ V,
                                                   unsigned short* __restrict__ VT) {
    __shared__ unsigned short lt[64 * 72];
    const int bh = blockIdx.x >> 5;
    const int kt = blockIdx.x & 31;
    const float* Vb = V + (size_t)bh * (SDIM * DDIM) + (size_t)kt * 64 * DDIM;
    unsigned short* VTb = VT + (size_t)bh * (DDIM * SDIM) + kt * 64;
    const int t = threadIdx.x;
    {
        const int kl = t >> 2, dg = t & 3;
        const float* vp = Vb + kl * DDIM + dg * 16;
        f32x4_t v0 = *(const f32x4_t*)vp;
        f32x4_t v1 = *(const f32x4_t*)(vp + 4);
        f32x4_t v2 = *(const f32x4_t*)(vp + 8);
        f32x4_t v3 = *(const f32x4_t*)(vp + 12);
#pragma unroll
        for (int j = 0; j < 16; ++j) {
            float f = (j < 4) ? v0[j] : (j < 8) ? v1[j - 4] : (j < 12) ? v2[j - 8] : v3[j - 12];
            lt[(dg * 16 + j) * 72 + kl] = f2bf(f);
        }
    }
    __syncthreads();
    {
        const int d = t >> 2, kg = t & 3;
        bf16x8_t w0 = *(const bf16x8_t*)&lt[d * 72 + kg * 16];
        bf16x8_t w1 = *(const bf16x8_t*)&lt[d * 72 + kg * 16 + 8];
        *(bf16x8_t*)(VTb + (size_t)d * SDIM + kg * 16) = w0;
        *(bf16x8_t*)(VTb + (size_t)d * SDIM + kg * 16 + 8) = w1;
    }
}

// ---------- main: LDS-staged K/V (contiguous loads), full-line attn stores ----------
__global__ __launch_bounds__(128, 2) void sdpa_main_kernel(
    const float* __restrict__ Q, const unsigned short* __restrict__ Kb,
    const unsigned short* __restrict__ VT, float* __restrict__ out,
    float* __restrict__ attn)
{
    __shared__ __align__(16) unsigned short Klds[KBLK * DDIM];  // 8KB, swizzled rows
    __shared__ __align__(16) unsigned short Vlds[DDIM * KBLK];  // 8KB, swizzled rows
    __shared__ __align__(16) float pbuf[2][16 * 64];            // 8KB, per-wave transpose buf

    const int bid = blockIdx.x;
    const int bh  = bid >> 5;
    const int qt  = bid & 31;
    const int tid = threadIdx.x;
    const int lane = tid & 63;
    const int wv   = tid >> 6;     // 0..1
    const int l15  = lane & 15;
    const int hi   = lane >> 4;    // 0..3
    const int qbase = qt * 64 + wv * 32;

    const unsigned short* KbB = Kb + (size_t)bh * (SDIM * DDIM);
    const unsigned short* VTb = VT + (size_t)bh * (DDIM * SDIM);
    float* outW  = out  + ((size_t)bh * SDIM + qbase) * DDIM;
    float* attnW = attn + (size_t)bh * SDIM * SDIM + (size_t)qbase * SDIM;
    float* pb = pbuf[wv];

    const float SC = 0.18033688011112042f;  // (1/sqrt(64)) * log2(e)

    // ---- Q fragments (B operand), 2 sub-tiles, pre-scaled by SC
    const float* qp0 = Q + ((size_t)bh * SDIM + qbase + l15) * DDIM + hi * 8;
    const float* qp1 = qp0 + (size_t)16 * DDIM;
    const bf16x8_t aq0_0 = pack8s(*(const f32x4_t*)qp0,        *(const f32x4_t*)(qp0 + 4), SC);
    const bf16x8_t aq1_0 = pack8s(*(const f32x4_t*)(qp0 + 32), *(const f32x4_t*)(qp0 + 36), SC);
    const bf16x8_t aq0_1 = pack8s(*(const f32x4_t*)qp1,        *(const f32x4_t*)(qp1 + 4), SC);
    const bf16x8_t aq1_1 = pack8s(*(const f32x4_t*)(qp1 + 32), *(const f32x4_t*)(qp1 + 36), SC);

    // ---- staging helpers (contiguous full-line global access)
    auto stage_load_K = [&](int kbase, bf16x8_t kreg[4]) {
#pragma unroll
        for (int j = 0; j < 4; ++j)
            kreg[j] = *(const bf16x8_t*)(KbB + (size_t)kbase * DDIM + (j * 128 + tid) * 8);
    };
    auto stage_write_K = [&](const bf16x8_t kreg[4]) {
#pragma unroll
        for (int j = 0; j < 4; ++j) {
            const int b = (j * 128 + tid) * 16;
            const int row = b >> 7;
            *(bf16x8_t*)((char*)Klds + (b ^ ((row & 7) << 4))) = kreg[j];
        }
    };
    auto stage_load_V = [&](int kbase, bf16x8_t vreg[4]) {
#pragma unroll
        for (int j = 0; j < 4; ++j) {
            const int row = wv * 32 + j * 8 + (lane >> 3);
            vreg[j] = *(const bf16x8_t*)(VTb + (size_t)row * SDIM + kbase + (lane & 7) * 8);
        }
    };
    auto stage_write_V = [&](const bf16x8_t vreg[4]) {
#pragma unroll
        for (int j = 0; j < 4; ++j) {
            const int row = wv * 32 + j * 8 + (lane >> 3);
            const int b = row * 128 + (lane & 7) * 16;
            *(bf16x8_t*)((char*)Vlds + (b ^ ((row & 7) << 4))) = vreg[j];
        }
    };
    auto read_kc = [&](int s, int c) -> bf16x8_t {
        const int row = s * 16 + l15;
        const int b = row * 128 + c * 64 + hi * 16;
        return *(const bf16x8_t*)((char*)Klds + (b ^ ((row & 7) << 4)));
    };
    auto read_vv = [&](int dt, int c) -> bf16x8_t {
        const int row = dt * 16 + l15;
        const int b = row * 128 + c * 64 + hi * 16;
        return *(const bf16x8_t*)((char*)Vlds + (b ^ ((row & 7) << 4)));
    };

    // ================= pass A: row sums (K staged in LDS) =================
    float rs0 = 0.f, rs1 = 0.f;
    {
        bf16x8_t kreg[4];
        stage_load_K(0, kreg);
        stage_write_K(kreg);
        lds_sync();
        for (int kb = 0; kb < NIT; ++kb) {
            bf16x8_t knx[4];
            if (kb + 1 < NIT) stage_load_K((kb + 1) * KBLK, knx);
#pragma unroll
            for (int s = 0; s < 4; ++s) {
                bf16x8_t k0 = read_kc(s, 0), k1 = read_kc(s, 1);
                f32x4_t a0 = {0.f,0.f,0.f,0.f}, a1 = {0.f,0.f,0.f,0.f};
                a0 = __builtin_amdgcn_mfma_f32_16x16x32_bf16(k0, aq0_0, a0, 0, 0, 0);
                a0 = __builtin_amdgcn_mfma_f32_16x16x32_bf16(k1, aq1_0, a0, 0, 0, 0);
                a1 = __builtin_amdgcn_mfma_f32_16x16x32_bf16(k0, aq0_1, a1, 0, 0, 0);
                a1 = __builtin_amdgcn_mfma_f32_16x16x32_bf16(k1, aq1_1, a1, 0, 0, 0);
                rs0 += __builtin_amdgcn_exp2f(a0[0]) + __builtin_amdgcn_exp2f(a0[1])
                     + __builtin_amdgcn_exp2f(a0[2]) + __builtin_amdgcn_exp2f(a0[3]);
                rs1 += __builtin_amdgcn_exp2f(a1[0]) + __builtin_amdgcn_exp2f(a1[1])
                     + __builtin_amdgcn_exp2f(a1[2]) + __builtin_amdgcn_exp2f(a1[3]);
            }
            lds_sync();
            if (kb + 1 < NIT) stage_write_K(knx);
            lds_sync();
        }
    }
    rs0 += __shfl_xor(rs0, 16); rs0 += __shfl_xor(rs0, 32);
    rs1 += __shfl_xor(rs1, 16); rs1 += __shfl_xor(rs1, 32);
    const float nlg0 = __builtin_amdgcn_logf(rs0);
    const float nlg1 = __builtin_amdgcn_logf(rs1);

    // ================= pass B =================
    f32x4_t oacc0[4] = {{0.f,0.f,0.f,0.f},{0.f,0.f,0.f,0.f},{0.f,0.f,0.f,0.f},{0.f,0.f,0.f,0.f}};
    f32x4_t oacc1[4] = {{0.f,0.f,0.f,0.f},{0.f,0.f,0.f,0.f},{0.f,0.f,0.f,0.f},{0.f,0.f,0.f,0.f}};

    const int laneA = l15 + ((hi & 1) << 5);
    const int laneB = laneA + 16;
    const bool selHi = (hi >> 1) != 0;

    // p transpose-store through pbuf: full-line global writes
    auto store_sub = [&](const f32x4_t P[4], int t, int kbase) {
#pragma unroll
        for (int g = 0; g < 4; ++g) {
            const int c4 = (g * 4 + hi) ^ ((l15 & 7) << 1);
            *(f32x4_t*)(pb + l15 * 64 + c4 * 4) = P[g];
        }
        asm volatile("s_waitcnt lgkmcnt(0)" ::: "memory");
        __builtin_amdgcn_sched_barrier(0);
#pragma unroll
        for (int j = 0; j < 4; ++j) {
            const int row = j * 4 + (lane & 3);
            const int c4 = lane >> 2;
            f32x4_t v = *(const f32x4_t*)(pb + row * 64 + (c4 ^ ((row & 7) << 1)) * 4);
            __builtin_nontemporal_store(v,
                (f32x4_t*)(attnW + (size_t)(t * 16 + row) * SDIM + kbase + c4 * 4));
        }
        asm volatile("s_waitcnt lgkmcnt(0)" ::: "memory");
        __builtin_amdgcn_sched_barrier(0);
    };
    // shfl redistribution (R7-verified): P[4 groups] -> af[2]
    auto build_af = [&](const f32x4_t P[4], bf16x8_t af[2]) {
        unsigned int w0[4], w1[4];
#pragma unroll
        for (int s = 0; s < 4; ++s) {
            w0[s] = pack2(P[s][0], P[s][1]);
            w1[s] = pack2(P[s][2], P[s][3]);
        }
#pragma unroll
        for (int k2 = 0; k2 < 2; ++k2) {
            const int sL = 2 * k2, sH = 2 * k2 + 1;
            unsigned int W0a = (unsigned int)__shfl((int)w0[sL], laneA);
            unsigned int W0b = (unsigned int)__shfl((int)w0[sH], laneA);
            unsigned int W1a = (unsigned int)__shfl((int)w1[sL], laneA);
            unsigned int W1b = (unsigned int)__shfl((int)w1[sH], laneA);
            unsigned int W2a = (unsigned int)__shfl((int)w0[sL], laneB);
            unsigned int W2b = (unsigned int)__shfl((int)w0[sH], laneB);
            unsigned int W3a = (unsigned int)__shfl((int)w1[sL], laneB);
            unsigned int W3b = (unsigned int)__shfl((int)w1[sH], laneB);
            uint4s W;
            W.x = selHi ? W0b : W0a;
            W.y = selHi ? W1b : W1a;
            W.z = selHi ? W2b : W2a;
            W.w = selHi ? W3b : W3a;
            af[k2] = __builtin_bit_cast(bf16x8_t, W);
        }
    };

    {
        bf16x8_t kreg[4], vreg[4];
        stage_load_K(0, kreg);
        stage_load_V(0, vreg);
        stage_write_K(kreg);
        stage_write_V(vreg);
        lds_sync();
        for (int kb = 0; kb < NIT; ++kb) {
            const int kbase = kb * KBLK;
            bf16x8_t knx[4], vnx[4];
            if (kb + 1 < NIT) {
                stage_load_K(kbase + KBLK, knx);
                stage_load_V(kbase + KBLK, vnx);
            }

            // QK^T both sub-tiles (swapped: D rows = keys, cols = q)
            f32x4_t A0[4], A1[4];
#pragma unroll
            for (int s = 0; s < 4; ++s) {
                bf16x8_t k0 = read_kc(s, 0), k1 = read_kc(s, 1);
                f32x4_t a0 = {0.f,0.f,0.f,0.f}, a1 = {0.f,0.f,0.f,0.f};
                a0 = __builtin_amdgcn_mfma_f32_16x16x32_bf16(k0, aq0_0, a0, 0, 0, 0);
                a0 = __builtin_amdgcn_mfma_f32_16x16x32_bf16(k1, aq1_0, a0, 0, 0, 0);
                a1 = __builtin_amdgcn_mfma_f32_16x16x32_bf16(k0, aq0_1, a1, 0, 0, 0);
                a1 = __builtin_amdgcn_mfma_f32_16x16x32_bf16(k1, aq1_1, a1, 0, 0, 0);
                A0[s] = a0; A1[s] = a1;
            }

            // softmax -> normalized p
            f32x4_t P0[4], P1[4];
#pragma unroll
            for (int s = 0; s < 4; ++s) {
#pragma unroll
                for (int r = 0; r < 4; ++r) {
                    P0[s][r] = __builtin_amdgcn_exp2f(A0[s][r] - nlg0);
                    P1[s][r] = __builtin_amdgcn_exp2f(A1[s][r] - nlg1);
                }
            }

            // PV
            bf16x8_t af0[2], af1[2];
            build_af(P0, af0);
            build_af(P1, af1);
#pragma unroll
            for (int dt = 0; dt < 4; ++dt) {
                bf16x8_t v0 = read_vv(dt, 0), v1 = read_vv(dt, 1);
                oacc0[dt] = __builtin_amdgcn_mfma_f32_16x16x32_bf16(af0[0], v0, oacc0[dt], 0, 0, 0);
                oacc0[dt] = __builtin_amdgcn_mfma_f32_16x16x32_bf16(af0[1], v1, oacc0[dt], 0, 0, 0);
                oacc1[dt] = __builtin_amdgcn_mfma_f32_16x16x32_bf16(af1[0], v0, oacc1[dt], 0, 0, 0);
                oacc1[dt] = __builtin_amdgcn_mfma_f32_16x16x32_bf16(af1[1], v1, oacc1[dt], 0, 0, 0);
            }

            // attn stores (transposed, full-line)
            store_sub(P0, 0, kbase);
            store_sub(P1, 1, kbase);

            lds_sync();
            if (kb + 1 < NIT) {
                stage_write_K(knx);
                stage_write_V(vnx);
            }
            lds_sync();
        }
    }

    // --- epilogue: output (normalized)
#pragma unroll
    for (int dt = 0; dt < 4; ++dt) {
#pragma unroll
        for (int r = 0; r < 4; ++r) {
            outW[(size_t)(hi * 4 + r) * DDIM + dt * 16 + l15] = oacc0[dt][r];
            outW[(size_t)(16 + hi * 4 + r) * DDIM + dt * 16 + l15] = oacc1[dt][r];
        }
    }
}

extern "C" void kernel_launch(void* const* d_in, const int* in_sizes, int n_in,
                              void* d_out, int out_size, void* d_ws, size_t ws_size,
                              hipStream_t stream) {
    const float* Q = (const float*)d_in[0];
    const float* K = (const float*)d_in[1];
    const float* V = (const float*)d_in[2];
    float* out  = (float*)d_out;
    float* attn = out + (size_t)NBH * SDIM * DDIM;

    unsigned short* Kb = (unsigned short*)d_ws;
    unsigned short* VT = Kb + (size_t)NBH * SDIM * DDIM;

    cvt_k_kernel<<<dim3((NBH * SDIM * DDIM) / (256 * 8)), dim3(256), 0, stream>>>(K, Kb);
    tr_v_kernel<<<dim3(NBH * 32), dim3(256), 0, stream>>>(V, VT);

    sdpa_main_kernel<<<dim3(NBH * 32), dim3(128), 0, stream>>>(Q, Kb, VT, out, attn);
}

// Round 11
// 234.173 us; speedup vs baseline: 2.5172x; 1.0718x over previous
//
#include <hip/hip_runtime.h>
#include <hip/hip_bf16.h>

typedef short bf16x8_t __attribute__((ext_vector_type(8)));
typedef float f32x4_t __attribute__((ext_vector_type(4)));

#define SDIM 2048
#define DDIM 64
#define KBLK 64
#define NIT  (SDIM / KBLK)
#define NBH  48

__device__ __forceinline__ unsigned short f2bf(float f) {
    return __builtin_bit_cast(unsigned short, (__bf16)f);
}
__device__ __forceinline__ unsigned int pack2(float lo, float hi) {
    return ((unsigned int)f2bf(hi) << 16) | (unsigned int)f2bf(lo);
}
__device__ __forceinline__ bf16x8_t pack8(f32x4_t a, f32x4_t b) {
    bf16x8_t r;
    r[0] = (short)f2bf(a[0]); r[1] = (short)f2bf(a[1]);
    r[2] = (short)f2bf(a[2]); r[3] = (short)f2bf(a[3]);
    r[4] = (short)f2bf(b[0]); r[5] = (short)f2bf(b[1]);
    r[6] = (short)f2bf(b[2]); r[7] = (short)f2bf(b[3]);
    return r;
}
__device__ __forceinline__ bf16x8_t pack8s(f32x4_t a, f32x4_t b, float s) {
    bf16x8_t r;
    r[0] = (short)f2bf(a[0] * s); r[1] = (short)f2bf(a[1] * s);
    r[2] = (short)f2bf(a[2] * s); r[3] = (short)f2bf(a[3] * s);
    r[4] = (short)f2bf(b[0] * s); r[5] = (short)f2bf(b[1] * s);
    r[6] = (short)f2bf(b[2] * s); r[7] = (short)f2bf(b[3] * s);
    return r;
}
struct uint4s { unsigned int x, y, z, w; };

__device__ __forceinline__ void lds_sync() {
    asm volatile("s_waitcnt lgkmcnt(0)" ::: "memory");
    __builtin_amdgcn_s_barrier();
    asm volatile("" ::: "memory");
}

// ---------- prep 1: K fp32 -> bf16 (row-major) ----------
__global__ __launch_bounds__(256) void cvt_k_kernel(const float* __restrict__ K,
                                                    unsigned short* __restrict__ Kb) {
    size_t i = ((size_t)blockIdx.x * 256 + threadIdx.x) * 8;
    f32x4_t a = *(const f32x4_t*)(K + i);
    f32x4_t b = *(const f32x4_t*)(K + i + 4);
    *(bf16x8_t*)(Kb + i) = pack8(a, b);
}

// ---------- prep 2: V fp32 [bh][k][d] -> bf16 V^T [bh][d][k] ----------
__global__ __launch_bounds__(256) void tr_v_kernel(const float* __restrict__ V,
                                                   unsigned short* __restrict__ VT) {
    __shared__ unsigned short lt[64 * 72];
    const int bh = blockIdx.x >> 5;
    const int kt = blockIdx.x & 31;
    const float* Vb = V + (size_t)bh * (SDIM * DDIM) + (size_t)kt * 64 * DDIM;
    unsigned short* VTb = VT + (size_t)bh * (DDIM * SDIM) + kt * 64;
    const int t = threadIdx.x;
    {
        const int kl = t >> 2, dg = t & 3;
        const float* vp = Vb + kl * DDIM + dg * 16;
        f32x4_t v0 = *(const f32x4_t*)vp;
        f32x4_t v1 = *(const f32x4_t*)(vp + 4);
        f32x4_t v2 = *(const f32x4_t*)(vp + 8);
        f32x4_t v3 = *(const f32x4_t*)(vp + 12);
#pragma unroll
        for (int j = 0; j < 16; ++j) {
            float f = (j < 4) ? v0[j] : (j < 8) ? v1[j - 4] : (j < 12) ? v2[j - 8] : v3[j - 12];
            lt[(dg * 16 + j) * 72 + kl] = f2bf(f);
        }
    }
    __syncthreads();
    {
        const int d = t >> 2, kg = t & 3;
        bf16x8_t w0 = *(const bf16x8_t*)&lt[d * 72 + kg * 16];
        bf16x8_t w1 = *(const bf16x8_t*)&lt[d * 72 + kg * 16 + 8];
        *(bf16x8_t*)(VTb + (size_t)d * SDIM + kg * 16) = w0;
        *(bf16x8_t*)(VTb + (size_t)d * SDIM + kg * 16 + 8) = w1;
    }
}

// ---------- main: 128 q/block, dbuf LDS staging, full-line everywhere ----------
__global__ __launch_bounds__(256, 2) void sdpa_main_kernel(
    const float* __restrict__ Q, const unsigned short* __restrict__ Kb,
    const unsigned short* __restrict__ VT, float* __restrict__ out,
    float* __restrict__ attn)
{
    __shared__ __align__(16) unsigned short Klds[2][KBLK * DDIM];  // 2 x 8KB
    __shared__ __align__(16) unsigned short Vlds[2][KBLK * DDIM];  // 2 x 8KB
    __shared__ __align__(16) float pbuf[4][16 * 64];               // 16KB

    const int bid = blockIdx.x;
    const int bh  = bid >> 4;      // 48
    const int qt  = bid & 15;      // 16 tiles of 128 q
    const int tid = threadIdx.x;
    const int lane = tid & 63;
    const int wv   = tid >> 6;     // 0..3
    const int l15  = lane & 15;
    const int hi   = lane >> 4;    // 0..3
    const int qbase = qt * 128 + wv * 32;

    const unsigned short* KbB = Kb + (size_t)bh * (SDIM * DDIM);
    const unsigned short* VTb = VT + (size_t)bh * (DDIM * SDIM);
    float* outW  = out  + ((size_t)bh * SDIM + qbase) * DDIM;
    float* attnW = attn + (size_t)bh * SDIM * SDIM + (size_t)qbase * SDIM;
    float* pb = pbuf[wv];

    const float SC = 0.18033688011112042f;  // (1/sqrt(64)) * log2(e)

    // ---- Q fragments (B operand), 2 sub-tiles, pre-scaled by SC
    const float* qp0 = Q + ((size_t)bh * SDIM + qbase + l15) * DDIM + hi * 8;
    const float* qp1 = qp0 + (size_t)16 * DDIM;
    const bf16x8_t aq0_0 = pack8s(*(const f32x4_t*)qp0,        *(const f32x4_t*)(qp0 + 4), SC);
    const bf16x8_t aq1_0 = pack8s(*(const f32x4_t*)(qp0 + 32), *(const f32x4_t*)(qp0 + 36), SC);
    const bf16x8_t aq0_1 = pack8s(*(const f32x4_t*)qp1,        *(const f32x4_t*)(qp1 + 4), SC);
    const bf16x8_t aq1_1 = pack8s(*(const f32x4_t*)(qp1 + 32), *(const f32x4_t*)(qp1 + 36), SC);

    // ---- staging helpers (contiguous full-line global access; 256 threads)
    auto stage_load_K = [&](int kbase, bf16x8_t kreg[2]) {
#pragma unroll
        for (int j = 0; j < 2; ++j)
            kreg[j] = *(const bf16x8_t*)(KbB + (size_t)kbase * DDIM + (j * 256 + tid) * 8);
    };
    auto stage_write_K = [&](unsigned short* dst, const bf16x8_t kreg[2]) {
#pragma unroll
        for (int j = 0; j < 2; ++j) {
            const int b = (j * 256 + tid) * 16;
            const int row = b >> 7;
            *(bf16x8_t*)((char*)dst + (b ^ ((row & 7) << 4))) = kreg[j];
        }
    };
    auto stage_load_V = [&](int kbase, bf16x8_t vreg[2]) {
#pragma unroll
        for (int j = 0; j < 2; ++j) {
            const int row = j * 32 + (tid >> 3);
            vreg[j] = *(const bf16x8_t*)(VTb + (size_t)row * SDIM + kbase + (tid & 7) * 8);
        }
    };
    auto stage_write_V = [&](unsigned short* dst, const bf16x8_t vreg[2]) {
#pragma unroll
        for (int j = 0; j < 2; ++j) {
            const int row = j * 32 + (tid >> 3);
            const int b = row * 128 + (tid & 7) * 16;
            *(bf16x8_t*)((char*)dst + (b ^ ((row & 7) << 4))) = vreg[j];
        }
    };
    auto read_tile = [&](const unsigned short* src, int s, int c) -> bf16x8_t {
        const int row = s * 16 + l15;
        const int b = row * 128 + c * 64 + hi * 16;
        return *(const bf16x8_t*)((const char*)src + (b ^ ((row & 7) << 4)));
    };

    // ================= pass A: row sums (K staged, dbuf, 1 barrier/iter) =================
    float rs0 = 0.f, rs1 = 0.f;
    {
        bf16x8_t kreg[2];
        stage_load_K(0, kreg);
        stage_write_K(Klds[0], kreg);
        lds_sync();
        for (int kb = 0; kb < NIT; ++kb) {
            bf16x8_t knx[2];
            if (kb + 1 < NIT) stage_load_K((kb + 1) * KBLK, knx);
            const unsigned short* Kc = Klds[kb & 1];
#pragma unroll
            for (int s = 0; s < 4; ++s) {
                bf16x8_t k0 = read_tile(Kc, s, 0), k1 = read_tile(Kc, s, 1);
                f32x4_t a0 = {0.f,0.f,0.f,0.f}, a1 = {0.f,0.f,0.f,0.f};
                a0 = __builtin_amdgcn_mfma_f32_16x16x32_bf16(k0, aq0_0, a0, 0, 0, 0);
                a0 = __builtin_amdgcn_mfma_f32_16x16x32_bf16(k1, aq1_0, a0, 0, 0, 0);
                a1 = __builtin_amdgcn_mfma_f32_16x16x32_bf16(k0, aq0_1, a1, 0, 0, 0);
                a1 = __builtin_amdgcn_mfma_f32_16x16x32_bf16(k1, aq1_1, a1, 0, 0, 0);
                rs0 += __builtin_amdgcn_exp2f(a0[0]) + __builtin_amdgcn_exp2f(a0[1])
                     + __builtin_amdgcn_exp2f(a0[2]) + __builtin_amdgcn_exp2f(a0[3]);
                rs1 += __builtin_amdgcn_exp2f(a1[0]) + __builtin_amdgcn_exp2f(a1[1])
                     + __builtin_amdgcn_exp2f(a1[2]) + __builtin_amdgcn_exp2f(a1[3]);
            }
            if (kb + 1 < NIT) stage_write_K(Klds[(kb + 1) & 1], knx);
            lds_sync();
        }
    }
    rs0 += __shfl_xor(rs0, 16); rs0 += __shfl_xor(rs0, 32);
    rs1 += __shfl_xor(rs1, 16); rs1 += __shfl_xor(rs1, 32);
    const float nlg0 = __builtin_amdgcn_logf(rs0);
    const float nlg1 = __builtin_amdgcn_logf(rs1);

    // ================= pass B (dbuf K+V, 1 barrier/iter) =================
    f32x4_t oacc0[4] = {{0.f,0.f,0.f,0.f},{0.f,0.f,0.f,0.f},{0.f,0.f,0.f,0.f},{0.f,0.f,0.f,0.f}};
    f32x4_t oacc1[4] = {{0.f,0.f,0.f,0.f},{0.f,0.f,0.f,0.f},{0.f,0.f,0.f,0.f},{0.f,0.f,0.f,0.f}};

    const int laneA = l15 + ((hi & 1) << 5);
    const int laneB = laneA + 16;
    const bool selHi = (hi >> 1) != 0;

    // p transpose-store through pbuf: full-line global writes (R10-verified)
    auto store_sub = [&](const f32x4_t P[4], int t, int kbase) {
#pragma unroll
        for (int g = 0; g < 4; ++g) {
            const int c4 = (g * 4 + hi) ^ ((l15 & 7) << 1);
            *(f32x4_t*)(pb + l15 * 64 + c4 * 4) = P[g];
        }
        asm volatile("s_waitcnt lgkmcnt(0)" ::: "memory");
        __builtin_amdgcn_sched_barrier(0);
#pragma unroll
        for (int j = 0; j < 4; ++j) {
            const int row = j * 4 + (lane & 3);
            const int c4 = lane >> 2;
            f32x4_t v = *(const f32x4_t*)(pb + row * 64 + (c4 ^ ((row & 7) << 1)) * 4);
            __builtin_nontemporal_store(v,
                (f32x4_t*)(attnW + (size_t)(t * 16 + row) * SDIM + kbase + c4 * 4));
        }
        asm volatile("s_waitcnt lgkmcnt(0)" ::: "memory");
        __builtin_amdgcn_sched_barrier(0);
    };
    // shfl redistribution (R7-verified): P[4 groups] -> af[2]
    auto build_af = [&](const f32x4_t P[4], bf16x8_t af[2]) {
        unsigned int w0[4], w1[4];
#pragma unroll
        for (int s = 0; s < 4; ++s) {
            w0[s] = pack2(P[s][0], P[s][1]);
            w1[s] = pack2(P[s][2], P[s][3]);
        }
#pragma unroll
        for (int k2 = 0; k2 < 2; ++k2) {
            const int sL = 2 * k2, sH = 2 * k2 + 1;
            unsigned int W0a = (unsigned int)__shfl((int)w0[sL], laneA);
            unsigned int W0b = (unsigned int)__shfl((int)w0[sH], laneA);
            unsigned int W1a = (unsigned int)__shfl((int)w1[sL], laneA);
            unsigned int W1b = (unsigned int)__shfl((int)w1[sH], laneA);
            unsigned int W2a = (unsigned int)__shfl((int)w0[sL], laneB);
            unsigned int W2b = (unsigned int)__shfl((int)w0[sH], laneB);
            unsigned int W3a = (unsigned int)__shfl((int)w1[sL], laneB);
            unsigned int W3b = (unsigned int)__shfl((int)w1[sH], laneB);
            uint4s W;
            W.x = selHi ? W0b : W0a;
            W.y = selHi ? W1b : W1a;
            W.z = selHi ? W2b : W2a;
            W.w = selHi ? W3b : W3a;
            af[k2] = __builtin_bit_cast(bf16x8_t, W);
        }
    };

    {
        bf16x8_t kreg[2], vreg[2];
        stage_load_K(0, kreg);
        stage_load_V(0, vreg);
        stage_write_K(Klds[0], kreg);
        stage_write_V(Vlds[0], vreg);
        lds_sync();
        for (int kb = 0; kb < NIT; ++kb) {
            const int kbase = kb * KBLK;
            bf16x8_t knx[2], vnx[2];
            if (kb + 1 < NIT) {
                stage_load_K(kbase + KBLK, knx);
                stage_load_V(kbase + KBLK, vnx);
            }
            const unsigned short* Kc = Klds[kb & 1];
            const unsigned short* Vc = Vlds[kb & 1];

            // QK^T both sub-tiles (swapped: D rows = keys, cols = q)
            f32x4_t A0[4], A1[4];
#pragma unroll
            for (int s = 0; s < 4; ++s) {
                bf16x8_t k0 = read_tile(Kc, s, 0), k1 = read_tile(Kc, s, 1);
                f32x4_t a0 = {0.f,0.f,0.f,0.f}, a1 = {0.f,0.f,0.f,0.f};
                a0 = __builtin_amdgcn_mfma_f32_16x16x32_bf16(k0, aq0_0, a0, 0, 0, 0);
                a0 = __builtin_amdgcn_mfma_f32_16x16x32_bf16(k1, aq1_0, a0, 0, 0, 0);
                a1 = __builtin_amdgcn_mfma_f32_16x16x32_bf16(k0, aq0_1, a1, 0, 0, 0);
                a1 = __builtin_amdgcn_mfma_f32_16x16x32_bf16(k1, aq1_1, a1, 0, 0, 0);
                A0[s] = a0; A1[s] = a1;
            }

            // softmax -> normalized p
            f32x4_t P0[4], P1[4];
#pragma unroll
            for (int s = 0; s < 4; ++s) {
#pragma unroll
                for (int r = 0; r < 4; ++r) {
                    P0[s][r] = __builtin_amdgcn_exp2f(A0[s][r] - nlg0);
                    P1[s][r] = __builtin_amdgcn_exp2f(A1[s][r] - nlg1);
                }
            }

            // PV
            bf16x8_t af0[2], af1[2];
            build_af(P0, af0);
            build_af(P1, af1);
#pragma unroll
            for (int dt = 0; dt < 4; ++dt) {
                bf16x8_t v0 = read_tile(Vc, dt, 0), v1 = read_tile(Vc, dt, 1);
                oacc0[dt] = __builtin_amdgcn_mfma_f32_16x16x32_bf16(af0[0], v0, oacc0[dt], 0, 0, 0);
                oacc0[dt] = __builtin_amdgcn_mfma_f32_16x16x32_bf16(af0[1], v1, oacc0[dt], 0, 0, 0);
                oacc1[dt] = __builtin_amdgcn_mfma_f32_16x16x32_bf16(af1[0], v0, oacc1[dt], 0, 0, 0);
                oacc1[dt] = __builtin_amdgcn_mfma_f32_16x16x32_bf16(af1[1], v1, oacc1[dt], 0, 0, 0);
            }

            // attn stores (transposed, full-line)
            store_sub(P0, 0, kbase);
            store_sub(P1, 1, kbase);

            if (kb + 1 < NIT) {
                stage_write_K(Klds[(kb + 1) & 1], knx);
                stage_write_V(Vlds[(kb + 1) & 1], vnx);
            }
            lds_sync();
        }
    }

    // --- epilogue: output (normalized)
#pragma unroll
    for (int dt = 0; dt < 4; ++dt) {
#pragma unroll
        for (int r = 0; r < 4; ++r) {
            outW[(size_t)(hi * 4 + r) * DDIM + dt * 16 + l15] = oacc0[dt][r];
            outW[(size_t)(16 + hi * 4 + r) * DDIM + dt * 16 + l15] = oacc1[dt][r];
        }
    }
}

extern "C" void kernel_launch(void* const* d_in, const int* in_sizes, int n_in,
                              void* d_out, int out_size, void* d_ws, size_t ws_size,
                              hipStream_t stream) {
    const float* Q = (const float*)d_in[0];
    const float* K = (const float*)d_in[1];
    const float* V = (const float*)d_in[2];
    float* out  = (float*)d_out;
    float* attn = out + (size_t)NBH * SDIM * DDIM;

    unsigned short* Kb = (unsigned short*)d_ws;
    unsigned short* VT = Kb + (size_t)NBH * SDIM * DDIM;

    cvt_k_kernel<<<dim3((NBH * SDIM * DDIM) / (256 * 8)), dim3(256), 0, stream>>>(K, Kb);
    tr_v_kernel<<<dim3(NBH * 32), dim3(256), 0, stream>>>(V, VT);

    sdpa_main_kernel<<<dim3(NBH * 16), dim3(256), 0, stream>>>(Q, Kb, VT, out, attn);
}